// Round 5
// baseline (248.845 us; speedup 1.0000x reference)
//
#include <hip/hip_runtime.h>
#include <hip/hip_bf16.h>

typedef unsigned short u16;
typedef float  f32x16 __attribute__((ext_vector_type(16)));
typedef short  bf16x8 __attribute__((ext_vector_type(8)));
typedef u16    u16x8  __attribute__((ext_vector_type(8)));

#define CDIM 1024
#define HW   16384

typedef const void __attribute__((address_space(1))) gvoid;
typedef void __attribute__((address_space(3))) svoid;

__device__ __forceinline__ u16 f2bf(float f) {
    unsigned u = __float_as_uint(f);
    u += 0x7fffu + ((u >> 16) & 1u);            // RNE
    return (u16)(u >> 16);
}
__device__ __forceinline__ float bf2f(u16 h) { return __uint_as_float(((unsigned)h) << 16); }

__device__ __forceinline__ f32x16 mfma32(bf16x8 a, bf16x8 b, f32x16 c) {
    return __builtin_amdgcn_mfma_f32_32x32x16_bf16(a, b, c, 0, 0, 0);
}

// ---------------- K1: x(f32) -> hi, lo (split bf16) + hiT (fused transpose) ----------------
__global__ __launch_bounds__(256) void k_convert(const float* __restrict__ x,
                                                 u16* __restrict__ hi, u16* __restrict__ lo,
                                                 u16* __restrict__ hiT)
{
    __shared__ u16 tile[64][72];
    const int pb = blockIdx.x;   // HW tile (0..255)
    const int cb = blockIdx.y;   // C tile  (0..15)
    const int tid = threadIdx.x;
#pragma unroll
    for (int pass = 0; pass < 4; ++pass) {
        const int i  = (tid >> 4) + (pass << 4);    // c-row in tile 0..63
        const int j4 = (tid & 15) << 2;             // p-col in tile
        const long gidx = (long)(cb * 64 + i) * HW + pb * 64 + j4;
        const float4 v = *(const float4*)(x + gidx);
        ushort4 h, l;
        h.x = f2bf(v.x); l.x = f2bf(v.x - bf2f(h.x));
        h.y = f2bf(v.y); l.y = f2bf(v.y - bf2f(h.y));
        h.z = f2bf(v.z); l.z = f2bf(v.z - bf2f(h.z));
        h.w = f2bf(v.w); l.w = f2bf(v.w - bf2f(h.w));
        *(ushort4*)(hi + gidx) = h;
        *(ushort4*)(lo + gidx) = l;
        tile[i][j4 + 0] = h.x; tile[i][j4 + 1] = h.y;
        tile[i][j4 + 2] = h.z; tile[i][j4 + 3] = h.w;
    }
    __syncthreads();
#pragma unroll
    for (int pass = 0; pass < 2; ++pass) {
        const int j  = (tid >> 3) + (pass << 5);    // p-row 0..63
        const int c8 = (tid & 7) << 3;
        u16x8 v;
#pragma unroll
        for (int q = 0; q < 8; ++q) v[q] = tile[c8 + q][j];
        *(u16x8*)(hiT + (long)(pb * 64 + j) * CDIM + cb * 64 + c8) = v;
    }
}

// ============ 128x128 GEMM — m97-exact structure: single 32 KB buffer, 2-barrier K-loop,
// ============ 4 waves (2x2, 64x64 each via 2x2 mfma_32x32x16), ~3 blocks/CU co-resident.
// A row-major (M x K), B row-major (N x K) -> C[M][N] = A.B^T
// EPI 0: write split-K partial to C + ks*csplit.   EPI 1: C = gamma*acc + X.

// Conflict-free LDS involution (R2/R4-proven, SQ_LDS_BANK_CONFLICT = 0):
// granule (row, s) of a 128x64 bf16 tile lives at u16 offset (row>>3)*512 + s*64 + ((row&7)^s)*8.
// Staged linearly by global_load_lds (wave-uniform base + lane*16B) with the inverse
// permutation applied to the global source address; reads apply the same involution.
__device__ __forceinline__ void stage_tile(const u16* __restrict__ gbase, long ldg,
                                           int ktile, u16* seg, int tid)
{
    const int lane = tid & 63;
    const int wv   = tid >> 6;
    const int s    = lane >> 3;                 // k-slot 0..7 (16B granules)
    const int r7   = (lane & 7) ^ s;            // row within 8-row region
    const int col  = s << 3;                    // element col of the granule
#pragma unroll
    for (int q = 0; q < 4; ++q) {
        const int j = wv + (q << 2);            // region 0..15 (8 rows each)
        const u16* src = gbase + (long)((j << 3) + r7) * ldg + (ktile << 6) + col;
        __builtin_amdgcn_global_load_lds((gvoid*)src, (svoid*)(seg + (j << 9)), 16, 0, 0);
    }
}

__device__ __forceinline__ bf16x8 rd_frag(const u16* seg, int row, int s)
{
    const int off = ((row >> 3) << 9) + (s << 6) + (((row & 7) ^ s) << 3);
    return *(const bf16x8*)(seg + off);
}

template<int EPI>
__global__ __launch_bounds__(256) void k_gemm(
    const u16* __restrict__ Amat, const u16* __restrict__ Bhi, const u16* __restrict__ Blo,
    long lda, long ldb, int kchunk, int nbnhalf,
    float* __restrict__ C, long ldc, long csplit,
    const float* __restrict__ X, const float* __restrict__ gamma)
{
    __shared__ u16 sA[8192];     // 128 x 64 bf16 = 16 KB
    __shared__ u16 sB[8192];

    const int tid  = threadIdx.x;
    const int lane = tid & 63;
    const int w    = tid >> 6;
    const int wm   = w >> 1;          // 0..1
    const int wn   = w & 1;           // 0..1
    const int l31  = lane & 31;
    const int lh   = lane >> 5;       // k-half within 16-wide k-chunk

    const int bn = blockIdx.x;
    const int bi = blockIdx.y;
    const int ks = blockIdx.z;

    const u16* Ab = Amat + (long)bi * 128 * lda + (long)ks * kchunk;
    const u16* Bb;
    if (EPI == 0) {   // combined B: first nbnhalf tiles from Bhi, rest from Blo
        Bb = (bn < nbnhalf) ? (Bhi + (long)bn * 128 * ldb)
                            : (Blo + (long)(bn - nbnhalf) * 128 * ldb);
    } else {
        Bb = Bhi + (long)bn * 128 * ldb;
    }
    Bb += (long)ks * kchunk;

    const int nkt = kchunk >> 6;

    f32x16 acc[2][2];
    {
        f32x16 z;
#pragma unroll
        for (int r = 0; r < 16; ++r) z[r] = 0.f;
        acc[0][0] = z; acc[0][1] = z; acc[1][0] = z; acc[1][1] = z;
    }

    for (int t = 0; t < nkt; ++t) {
        stage_tile(Ab, lda, t, sA, tid);
        stage_tile(Bb, ldb, t, sB, tid);
        __syncthreads();              // drains vmcnt(0): tile landed

#pragma unroll
        for (int kk = 0; kk < 4; ++kk) {
            const int s = (kk << 1) + lh;
            bf16x8 a0 = rd_frag(sA, wm * 64 + l31,      s);
            bf16x8 a1 = rd_frag(sA, wm * 64 + 32 + l31, s);
            bf16x8 b0 = rd_frag(sB, wn * 64 + l31,      s);
            bf16x8 b1 = rd_frag(sB, wn * 64 + 32 + l31, s);
            acc[0][0] = mfma32(a0, b0, acc[0][0]);
            acc[0][1] = mfma32(a0, b1, acc[0][1]);
            acc[1][0] = mfma32(a1, b0, acc[1][0]);
            acc[1][1] = mfma32(a1, b1, acc[1][1]);
        }
        __syncthreads();              // reads done before next stage overwrites
    }

    // -------- epilogue: 32x32 C/D layout (R1/R2-verified):
    // col = lane&31, row = (r&3) + 8*(r>>2) + 4*(lane>>5)
    if (EPI == 0) {
        float* Cb = C + (long)ks * csplit;
#pragma unroll
        for (int m = 0; m < 2; ++m)
#pragma unroll
            for (int n = 0; n < 2; ++n)
#pragma unroll
                for (int r = 0; r < 16; ++r) {
                    const int row = bi * 128 + wm * 64 + m * 32 + (r & 3) + ((r >> 2) << 3) + (lh << 2);
                    const int col = bn * 128 + wn * 64 + n * 32 + l31;
                    Cb[(long)row * ldc + col] = acc[m][n][r];
                }
    } else {
        const float gm = gamma[0];
#pragma unroll
        for (int m = 0; m < 2; ++m)
#pragma unroll
            for (int n = 0; n < 2; ++n)
#pragma unroll
                for (int r = 0; r < 16; ++r) {
                    const int row = bi * 128 + wm * 64 + m * 32 + (r & 3) + ((r >> 2) << 3) + (lh << 2);
                    const int col = bn * 128 + wn * 64 + n * 32 + l31;
                    const long idx = (long)row * ldc + col;
                    C[idx] = gm * acc[m][n][r] + X[idx];
                }
    }
}

// ---------------- K2b: Esym = sum_ks (E1 + E2 + E2^T), E12[ks][1024][2048] ----------------
__global__ __launch_bounds__(256) void k_symmetrize(const float* __restrict__ E12,
                                                    float* __restrict__ Esym)
{
    __shared__ float tr[64][65];
    const int jb = blockIdx.x, ib = blockIdx.y, tid = threadIdx.x;
    float4 accv[4];
#pragma unroll
    for (int e4 = 0; e4 < 4; ++e4) {
        const int e = tid + (e4 << 8);
        const int i = e >> 4, j4 = (e & 15) << 2;
        float ax = 0, ay = 0, az = 0, aw = 0, bx = 0, by = 0, bz = 0, bw = 0;
#pragma unroll
        for (int ks = 0; ks < 8; ++ks) {
            const float* base = E12 + (long)ks * (1024 * 2048);
            float4 p1 = *(const float4*)(base + (long)(ib * 64 + i) * 2048 + jb * 64 + j4);
            float4 p2 = *(const float4*)(base + (long)(ib * 64 + i) * 2048 + 1024 + jb * 64 + j4);
            float4 p3 = *(const float4*)(base + (long)(jb * 64 + i) * 2048 + 1024 + ib * 64 + j4);
            ax += p1.x + p2.x; ay += p1.y + p2.y; az += p1.z + p2.z; aw += p1.w + p2.w;
            bx += p3.x; by += p3.y; bz += p3.z; bw += p3.w;
        }
        accv[e4] = make_float4(ax, ay, az, aw);
        tr[i][j4 + 0] = bx; tr[i][j4 + 1] = by; tr[i][j4 + 2] = bz; tr[i][j4 + 3] = bw;
    }
    __syncthreads();
#pragma unroll
    for (int e4 = 0; e4 < 4; ++e4) {
        const int e = tid + (e4 << 8);
        const int i = e >> 4, j4 = (e & 15) << 2;
        float4 o = accv[e4];
        o.x += tr[j4 + 0][i]; o.y += tr[j4 + 1][i]; o.z += tr[j4 + 2][i]; o.w += tr[j4 + 3][i];
        *(float4*)(Esym + (long)(ib * 64 + i) * CDIM + jb * 64 + j4) = o;
    }
}

// ---------------- K3: att = softmax(-E) rows, stored bf16 ----------------
__global__ __launch_bounds__(256) void k_softmax(const float* __restrict__ E, u16* __restrict__ att)
{
    __shared__ float red[4];
    __shared__ float bcast;
    const int row = blockIdx.x, tid = threadIdx.x;
    const float4 v = ((const float4*)(E + (long)row * CDIM))[tid];

    float m = fminf(fminf(v.x, v.y), fminf(v.z, v.w));
#pragma unroll
    for (int s = 32; s > 0; s >>= 1) m = fminf(m, __shfl_down(m, s));
    if ((tid & 63) == 0) red[tid >> 6] = m;
    __syncthreads();
    if (tid == 0) bcast = fminf(fminf(red[0], red[1]), fminf(red[2], red[3]));
    __syncthreads();
    m = bcast;  // row min of E == row max of -E

    const float px = expf(m - v.x), py = expf(m - v.y), pz = expf(m - v.z), pw = expf(m - v.w);
    float s4 = px + py + pz + pw;
#pragma unroll
    for (int s = 32; s > 0; s >>= 1) s4 += __shfl_down(s4, s);
    if ((tid & 63) == 0) red[tid >> 6] = s4;
    __syncthreads();
    if (tid == 0) bcast = red[0] + red[1] + red[2] + red[3];
    __syncthreads();
    const float inv = 1.0f / bcast;

    ushort4 o;
    o.x = f2bf(px * inv); o.y = f2bf(py * inv); o.z = f2bf(pz * inv); o.w = f2bf(pw * inv);
    ((ushort4*)(att + (long)row * CDIM))[tid] = o;
}

extern "C" void kernel_launch(void* const* d_in, const int* in_sizes, int n_in,
                              void* d_out, int out_size, void* d_ws, size_t ws_size,
                              hipStream_t stream)
{
    (void)in_sizes; (void)n_in; (void)out_size; (void)ws_size;
    const float* x = (const float*)d_in[0];
    const float* gamma = (const float*)d_in[1];
    float* out = (float*)d_out;
    char* ws = (char*)d_ws;

    // Workspace (102 MiB, proven to fit): hi | lo | hiT | Esym | att.
    // Split-K partials (64 MiB) live in d_out, fully overwritten by the final GEMM.
    u16*   hi   = (u16*)ws;                         // 32 MiB
    u16*   lo   = (u16*)(ws + (32ull << 20));       // 32 MiB
    u16*   hiT  = (u16*)(ws + (64ull << 20));       // 32 MiB
    float* Esym = (float*)(ws + (96ull << 20));     //  4 MiB
    u16*   att  = (u16*)(ws + (100ull << 20));      //  2 MiB
    float* E12  = out;                              // 64 MiB scratch (== out buffer)

    k_convert<<<dim3(256, 16), 256, 0, stream>>>(x, hi, lo, hiT);
    // Energy: combined GEMM  M=1024, N=2048 (hi||lo), K=16384, split-K=8.
    // grid 16x8x8 = 1024 blocks; 32 KB LDS -> ~3 blocks/CU co-resident (m97 mechanism).
    k_gemm<0><<<dim3(16, 8, 8), 256, 0, stream>>>(hi, hi, lo, (long)HW, (long)HW, 2048, 8,
                                                  E12, 2048L, 1024L * 2048L, nullptr, nullptr);
    k_symmetrize<<<dim3(16, 16), 256, 0, stream>>>(E12, Esym);
    k_softmax<<<1024, 256, 0, stream>>>(Esym, att);
    // Out: GEMM  M=1024, N=16384, K=1024; epilogue gamma*acc + x.  grid 128x8 = 1024 blocks.
    k_gemm<1><<<dim3(128, 8, 1), 256, 0, stream>>>(att, hiT, nullptr, 1024L, 1024L, 1024, 0,
                                                   out, (long)HW, 0L, x, gamma);
}

// Round 6
// 241.760 us; speedup vs baseline: 1.0293x; 1.0293x over previous
//
#include <hip/hip_runtime.h>
#include <hip/hip_bf16.h>

typedef unsigned short u16;
typedef float  f32x16 __attribute__((ext_vector_type(16)));
typedef short  bf16x8 __attribute__((ext_vector_type(8)));
typedef u16    u16x8  __attribute__((ext_vector_type(8)));

#define CDIM 1024
#define HW   16384

typedef const void __attribute__((address_space(1))) gvoid;
typedef void __attribute__((address_space(3))) svoid;

__device__ __forceinline__ u16 f2bf(float f) {
    unsigned u = __float_as_uint(f);
    u += 0x7fffu + ((u >> 16) & 1u);            // RNE
    return (u16)(u >> 16);
}
__device__ __forceinline__ float bf2f(u16 h) { return __uint_as_float(((unsigned)h) << 16); }

__device__ __forceinline__ f32x16 mfma32(bf16x8 a, bf16x8 b, f32x16 c) {
    return __builtin_amdgcn_mfma_f32_32x32x16_bf16(a, b, c, 0, 0, 0);
}

// ---------------- K1: x(f32) -> hi, lo (split bf16) + hiT (fused transpose) ----------------
__global__ __launch_bounds__(256) void k_convert(const float* __restrict__ x,
                                                 u16* __restrict__ hi, u16* __restrict__ lo,
                                                 u16* __restrict__ hiT)
{
    __shared__ u16 tile[64][72];
    const int pb = blockIdx.x;   // HW tile (0..255)
    const int cb = blockIdx.y;   // C tile  (0..15)
    const int tid = threadIdx.x;
#pragma unroll
    for (int pass = 0; pass < 4; ++pass) {
        const int i  = (tid >> 4) + (pass << 4);    // c-row in tile 0..63
        const int j4 = (tid & 15) << 2;             // p-col in tile
        const long gidx = (long)(cb * 64 + i) * HW + pb * 64 + j4;
        const float4 v = *(const float4*)(x + gidx);
        ushort4 h, l;
        h.x = f2bf(v.x); l.x = f2bf(v.x - bf2f(h.x));
        h.y = f2bf(v.y); l.y = f2bf(v.y - bf2f(h.y));
        h.z = f2bf(v.z); l.z = f2bf(v.z - bf2f(h.z));
        h.w = f2bf(v.w); l.w = f2bf(v.w - bf2f(h.w));
        *(ushort4*)(hi + gidx) = h;
        *(ushort4*)(lo + gidx) = l;
        tile[i][j4 + 0] = h.x; tile[i][j4 + 1] = h.y;
        tile[i][j4 + 2] = h.z; tile[i][j4 + 3] = h.w;
    }
    __syncthreads();
#pragma unroll
    for (int pass = 0; pass < 2; ++pass) {
        const int j  = (tid >> 3) + (pass << 5);    // p-row 0..63
        const int c8 = (tid & 7) << 3;
        u16x8 v;
#pragma unroll
        for (int q = 0; q < 8; ++q) v[q] = tile[c8 + q][j];
        *(u16x8*)(hiT + (long)(pb * 64 + j) * CDIM + cb * 64 + c8) = v;
    }
}

// ---- LDS involution placement (R4/R5-proven staging/read pair) ----
// Granule (row, s) of a 128x64 bf16 tile lives at u16 offset (row>>3)*512 + s*64 + ((row&7)^s)*8.
// Staged linearly by global_load_lds (wave-uniform base + lane*16B) with the inverse
// permutation on the global source address; reads apply the same involution.
// 512-thread version: 8 waves x 2 regions each.
__device__ __forceinline__ void stage_tile(const u16* __restrict__ gbase, long ldg,
                                           int ktile, u16* seg, int tid)
{
    const int lane = tid & 63;
    const int wv   = tid >> 6;                  // 0..7
    const int s    = lane >> 3;                 // k-slot 0..7 (16B granules)
    const int r7   = (lane & 7) ^ s;            // row within 8-row region
    const int col  = s << 3;                    // element col of the granule
#pragma unroll
    for (int q = 0; q < 2; ++q) {
        const int j = wv + (q << 3);            // region 0..15 (8 rows each)
        const u16* src = gbase + (long)((j << 3) + r7) * ldg + (ktile << 6) + col;
        __builtin_amdgcn_global_load_lds((gvoid*)src, (svoid*)(seg + (j << 9)), 16, 0, 0);
    }
}

__device__ __forceinline__ bf16x8 rd_frag(const u16* seg, int row, int s)
{
    const int off = ((row >> 3) << 9) + (s << 6) + (((row & 7) ^ s) << 3);
    return *(const bf16x8*)(seg + off);
}

// ---------------- K2: E1p = H*H^T, E2p = H*L^T (split-K partials) ----------------
// R1-proven structure (697 TF): 128x128 tile, BK=64, 3-tile staging (A shared),
// double-buffered, stage-early + vmcnt(0)+syncthreads.  NEW: 512 threads — waves 0-3
// compute E1 (sBh), waves 4-7 compute E2 (sBl) -> 2 waves/SIMD co-schedule MFMA vs LDS.
__global__ __launch_bounds__(512) void k_energy(const u16* __restrict__ hi, const u16* __restrict__ lo,
                                                float* __restrict__ E1p, float* __restrict__ E2p,
                                                int kchunk)
{
    __shared__ u16 sA [2][8192];
    __shared__ u16 sBh[2][8192];
    __shared__ u16 sBl[2][8192];

    const int tid  = threadIdx.x;
    const int lane = tid & 63;
    const int w    = tid >> 6;
    const int which = w >> 2;         // 0: E1 (hi.hi^T)   1: E2 (hi.lo^T)
    const int wm    = (w >> 1) & 1;
    const int wn    = w & 1;
    const int l31   = lane & 31;
    const int lh    = lane >> 5;      // k-half

    const int bj = blockIdx.x, bi = blockIdx.y, ks = blockIdx.z;
    const long k0 = (long)ks * kchunk;
    const int nkt = kchunk >> 6;

    const u16* Ab = hi + (long)bi * 128 * HW + k0;
    const u16* Bh = hi + (long)bj * 128 * HW + k0;
    const u16* Bl = lo + (long)bj * 128 * HW + k0;

    f32x16 acc[2][2];
    {
        f32x16 z;
#pragma unroll
        for (int r = 0; r < 16; ++r) z[r] = 0.f;
        acc[0][0] = z; acc[0][1] = z; acc[1][0] = z; acc[1][1] = z;
    }

    stage_tile(Ab, HW, 0, sA[0],  tid);
    stage_tile(Bh, HW, 0, sBh[0], tid);
    stage_tile(Bl, HW, 0, sBl[0], tid);
    asm volatile("s_waitcnt vmcnt(0)" ::: "memory");
    __syncthreads();

    int buf = 0;
    for (int t = 0; t < nkt; ++t) {
        if (t + 1 < nkt) {
            stage_tile(Ab, HW, t + 1, sA[buf ^ 1],  tid);
            stage_tile(Bh, HW, t + 1, sBh[buf ^ 1], tid);
            stage_tile(Bl, HW, t + 1, sBl[buf ^ 1], tid);
        }
        const u16* aSeg = sA[buf];
        const u16* bSeg = which ? sBl[buf] : sBh[buf];
#pragma unroll
        for (int kk = 0; kk < 4; ++kk) {
            const int s = (kk << 1) + lh;
            bf16x8 a0 = rd_frag(aSeg, wm * 64 + l31,      s);
            bf16x8 a1 = rd_frag(aSeg, wm * 64 + 32 + l31, s);
            bf16x8 b0 = rd_frag(bSeg, wn * 64 + l31,      s);
            bf16x8 b1 = rd_frag(bSeg, wn * 64 + 32 + l31, s);
            acc[0][0] = mfma32(a0, b0, acc[0][0]);
            acc[0][1] = mfma32(a0, b1, acc[0][1]);
            acc[1][0] = mfma32(a1, b0, acc[1][0]);
            acc[1][1] = mfma32(a1, b1, acc[1][1]);
        }
        asm volatile("s_waitcnt vmcnt(0)" ::: "memory");
        __syncthreads();
        buf ^= 1;
    }

    // 32x32 C/D layout (R1/R2-verified): col = lane&31, row = (r&3) + 8*(r>>2) + 4*(lane>>5)
    float* e = (which ? E2p : E1p) + (long)ks * (CDIM * CDIM);
#pragma unroll
    for (int m = 0; m < 2; ++m)
#pragma unroll
        for (int n = 0; n < 2; ++n)
#pragma unroll
            for (int r = 0; r < 16; ++r) {
                const int row = bi * 128 + wm * 64 + m * 32 + (r & 3) + ((r >> 2) << 3) + (lh << 2);
                const int col = bj * 128 + wn * 64 + n * 32 + l31;
                e[(long)row * CDIM + col] = acc[m][n][r];
            }
}

// ---------------- K2b: Esym = sum_ks (E1p + E2p + E2p^T), nsplit = 4 ----------------
__global__ __launch_bounds__(256) void k_symmetrize(const float* __restrict__ E1p,
                                                    const float* __restrict__ E2p,
                                                    float* __restrict__ Esym)
{
    __shared__ float tr[64][65];
    const int jb = blockIdx.x, ib = blockIdx.y, tid = threadIdx.x;
    float4 accv[4];
#pragma unroll
    for (int e4 = 0; e4 < 4; ++e4) {
        const int e = tid + (e4 << 8);
        const int i = e >> 4, j4 = (e & 15) << 2;
        float ax = 0, ay = 0, az = 0, aw = 0, bx = 0, by = 0, bz = 0, bw = 0;
#pragma unroll
        for (int ks = 0; ks < 4; ++ks) {
            const long base = (long)ks * (CDIM * CDIM);
            float4 p1 = *(const float4*)(E1p + base + (long)(ib * 64 + i) * CDIM + jb * 64 + j4);
            float4 p2 = *(const float4*)(E2p + base + (long)(ib * 64 + i) * CDIM + jb * 64 + j4);
            float4 p3 = *(const float4*)(E2p + base + (long)(jb * 64 + i) * CDIM + ib * 64 + j4);
            ax += p1.x + p2.x; ay += p1.y + p2.y; az += p1.z + p2.z; aw += p1.w + p2.w;
            bx += p3.x; by += p3.y; bz += p3.z; bw += p3.w;
        }
        accv[e4] = make_float4(ax, ay, az, aw);
        tr[i][j4 + 0] = bx; tr[i][j4 + 1] = by; tr[i][j4 + 2] = bz; tr[i][j4 + 3] = bw;
    }
    __syncthreads();
#pragma unroll
    for (int e4 = 0; e4 < 4; ++e4) {
        const int e = tid + (e4 << 8);
        const int i = e >> 4, j4 = (e & 15) << 2;
        float4 o = accv[e4];
        o.x += tr[j4 + 0][i]; o.y += tr[j4 + 1][i]; o.z += tr[j4 + 2][i]; o.w += tr[j4 + 3][i];
        *(float4*)(Esym + (long)(ib * 64 + i) * CDIM + jb * 64 + j4) = o;
    }
}

// ---------------- K3: att = softmax(-E) rows, stored bf16 ----------------
__global__ __launch_bounds__(256) void k_softmax(const float* __restrict__ E, u16* __restrict__ att)
{
    __shared__ float red[4];
    __shared__ float bcast;
    const int row = blockIdx.x, tid = threadIdx.x;
    const float4 v = ((const float4*)(E + (long)row * CDIM))[tid];

    float m = fminf(fminf(v.x, v.y), fminf(v.z, v.w));
#pragma unroll
    for (int s = 32; s > 0; s >>= 1) m = fminf(m, __shfl_down(m, s));
    if ((tid & 63) == 0) red[tid >> 6] = m;
    __syncthreads();
    if (tid == 0) bcast = fminf(fminf(red[0], red[1]), fminf(red[2], red[3]));
    __syncthreads();
    m = bcast;  // row min of E == row max of -E

    const float px = expf(m - v.x), py = expf(m - v.y), pz = expf(m - v.z), pw = expf(m - v.w);
    float s4 = px + py + pz + pw;
#pragma unroll
    for (int s = 32; s > 0; s >>= 1) s4 += __shfl_down(s4, s);
    if ((tid & 63) == 0) red[tid >> 6] = s4;
    __syncthreads();
    if (tid == 0) bcast = red[0] + red[1] + red[2] + red[3];
    __syncthreads();
    const float inv = 1.0f / bcast;

    ushort4 o;
    o.x = f2bf(px * inv); o.y = f2bf(py * inv); o.z = f2bf(pz * inv); o.w = f2bf(pw * inv);
    ((ushort4*)(att + (long)row * CDIM))[tid] = o;
}

// ---------------- K4: out = gamma * (att @ q) + x ----------------
// R1 structure, 512 threads: 8 waves (2m x 4n), each 64x32 output; 64 KB LDS -> 2 blocks/CU.
__global__ __launch_bounds__(512) void k_out(const u16* __restrict__ att, const u16* __restrict__ qT,
                                             const float* __restrict__ x, const float* __restrict__ gamma,
                                             float* __restrict__ out)
{
    __shared__ u16 sA[2][8192];
    __shared__ u16 sB[2][8192];

    const int tid  = threadIdx.x;
    const int lane = tid & 63;
    const int w    = tid >> 6;
    const int wm   = w >> 2;          // 0..1
    const int wn   = w & 3;           // 0..3 (32-col strip)
    const int l31  = lane & 31;
    const int lh   = lane >> 5;

    const int bp = blockIdx.x, bi = blockIdx.y;

    const u16* Ab = att + (long)bi * 128 * CDIM;
    const u16* Bb = qT  + (long)bp * 128 * CDIM;

    f32x16 acc[2];
    {
        f32x16 z;
#pragma unroll
        for (int r = 0; r < 16; ++r) z[r] = 0.f;
        acc[0] = z; acc[1] = z;
    }

    stage_tile(Ab, CDIM, 0, sA[0], tid);
    stage_tile(Bb, CDIM, 0, sB[0], tid);
    asm volatile("s_waitcnt vmcnt(0)" ::: "memory");
    __syncthreads();

    int buf = 0;
    for (int t = 0; t < 16; ++t) {
        if (t < 15) {
            stage_tile(Ab, CDIM, t + 1, sA[buf ^ 1], tid);
            stage_tile(Bb, CDIM, t + 1, sB[buf ^ 1], tid);
        }
#pragma unroll
        for (int kk = 0; kk < 4; ++kk) {
            const int s = (kk << 1) + lh;
            bf16x8 a0 = rd_frag(sA[buf], wm * 64 + l31,      s);
            bf16x8 a1 = rd_frag(sA[buf], wm * 64 + 32 + l31, s);
            bf16x8 b  = rd_frag(sB[buf], wn * 32 + l31,      s);
            acc[0] = mfma32(a0, b, acc[0]);
            acc[1] = mfma32(a1, b, acc[1]);
        }
        asm volatile("s_waitcnt vmcnt(0)" ::: "memory");
        __syncthreads();
        buf ^= 1;
    }

    const float gm = gamma[0];
#pragma unroll
    for (int m = 0; m < 2; ++m)
#pragma unroll
        for (int r = 0; r < 16; ++r) {
            const int row = bi * 128 + wm * 64 + m * 32 + (r & 3) + ((r >> 2) << 3) + (lh << 2);
            const int col = bp * 128 + wn * 32 + l31;
            const long idx = (long)row * HW + col;
            out[idx] = gm * acc[m][r] + x[idx];
        }
}

extern "C" void kernel_launch(void* const* d_in, const int* in_sizes, int n_in,
                              void* d_out, int out_size, void* d_ws, size_t ws_size,
                              hipStream_t stream)
{
    (void)in_sizes; (void)n_in; (void)out_size; (void)ws_size;
    const float* x = (const float*)d_in[0];
    const float* gamma = (const float*)d_in[1];
    float* out = (float*)d_out;
    char* ws = (char*)d_ws;

    // Workspace (102 MiB, proven to fit): hi | lo | hiT | Esym | att.
    // Split-K partials (2 x 16 MiB) live in d_out (64 MiB), fully overwritten by k_out.
    u16*   hi   = (u16*)ws;                         // 32 MiB
    u16*   lo   = (u16*)(ws + (32ull << 20));       // 32 MiB
    u16*   hiT  = (u16*)(ws + (64ull << 20));       // 32 MiB
    float* Esym = (float*)(ws + (96ull << 20));     //  4 MiB
    u16*   att  = (u16*)(ws + (100ull << 20));      //  2 MiB
    float* E1p  = out;                              // 16 MiB (4 splits x 4 MiB)
    float* E2p  = out + 4ull * CDIM * CDIM;         // 16 MiB

    k_convert<<<dim3(256, 16), 256, 0, stream>>>(x, hi, lo, hiT);
    // Energy: 8x8 tile grid x split-K 4 = 256 blocks (1/CU), kchunk = 4096.
    k_energy<<<dim3(8, 8, 4), 512, 0, stream>>>(hi, lo, E1p, E2p, 4096);
    k_symmetrize<<<dim3(16, 16), 256, 0, stream>>>(E1p, E2p, Esym);
    k_softmax<<<1024, 256, 0, stream>>>(Esym, att);
    // Out: GEMM M=1024, N=16384, K=1024; epilogue gamma*acc + x.  grid 128x8, 2 blocks/CU.
    k_out<<<dim3(128, 8), 512, 0, stream>>>(att, hiT, x, gamma, out);
}